// Round 6
// baseline (731.188 us; speedup 1.0000x reference)
//
#include <hip/hip_runtime.h>
#include <hip/hip_bf16.h>
#include <stdint.h>

#define N_TOK 2048
#define DM    2048
#define NEXP  64
#define TOPK  4
#define HEXP  512
#define CAPC  512
#define NSH   2
#define HSH   2048
#define RTB   8

typedef __attribute__((ext_vector_type(8))) short short8;
typedef __attribute__((ext_vector_type(4))) float f32x4;
typedef __attribute__((ext_vector_type(4))) float f4;
typedef __attribute__((ext_vector_type(4))) unsigned uint4v;

// Direct global->LDS DMA, 16B per lane. LDS dest = wave-uniform base + lane*16.
#define GLDS16(g, l) __builtin_amdgcn_global_load_lds(                     \
    (const __attribute__((address_space(1))) void*)(g),                    \
    (__attribute__((address_space(3))) void*)(l), 16, 0, 0)

// Counted VMEM wait: NEVER 0 inside the k-loop (loads stay in flight).
#define VMWAIT(N) asm volatile("s_waitcnt vmcnt(" #N ")" ::: "memory")
#define BARX() do { asm volatile("" ::: "memory");                          \
                    __builtin_amdgcn_s_barrier();                           \
                    asm volatile("" ::: "memory"); } while (0)

static __device__ __forceinline__ unsigned short f2bf(float f) {
  union { float f; unsigned u; } v; v.f = f;
  unsigned r = v.u + 0x7FFFu + ((v.u >> 16) & 1u);   // RNE
  return (unsigned short)(r >> 16);
}

// Bijective XCD-chunk swizzle (requires nwg % 8 == 0): hw ids with the same
// (id & 7) — likely same XCD — get a CONTIGUOUS logical range, so blocks
// sharing an A-tile co-locate in one L2.
static __device__ __forceinline__ int swz_xcd(int id, int nwg) {
  return (id & 7) * (nwg >> 3) + (id >> 3);
}

// ---------------------------------------------------------------- convert x
__global__ __launch_bounds__(256) void k_convert(const float* __restrict__ x,
                                                 unsigned short* __restrict__ xb) {
  int i = (blockIdx.x * 256 + threadIdx.x) * 8;
  f4 a = *(const f4*)(x + i);
  f4 b = *(const f4*)(x + i + 4);
  short8 o;
  o[0]=f2bf(a[0]); o[1]=f2bf(a[1]); o[2]=f2bf(a[2]); o[3]=f2bf(a[3]);
  o[4]=f2bf(b[0]); o[5]=f2bf(b[1]); o[6]=f2bf(b[2]); o[7]=f2bf(b[3]);
  *(short8*)(xb + i) = o;
}

// ---------------------------------------------------------------- router
#define ARGMAX_ROUND(S,I)                                            \
  { float bv = v; int bi = lane;                                     \
    _Pragma("unroll")                                                \
    for (int o = 32; o; o >>= 1) {                                   \
      float ov = __shfl_xor(bv, o); int oi = __shfl_xor(bi, o);      \
      if (ov > bv || (ov == bv && oi < bi)) { bv = ov; bi = oi; }    \
    }                                                                \
    S = bv; I = bi; if (lane == bi) v = -1.f; }

__global__ __launch_bounds__(256) void k_router(const float* __restrict__ x,
    const float* __restrict__ Wr, const float* __restrict__ bias,
    int* __restrict__ cnt, int* __restrict__ lists, float* __restrict__ wlist) {
  __shared__ float part[4][RTB][64];
  __shared__ float logits[RTB][64];
  int t = threadIdx.x;
  int e = t & 63, sl = t >> 6;
  int tok0 = blockIdx.x * RTB;
  const float* xp = x + (size_t)tok0 * DM;
  float acc[RTB];
#pragma unroll
  for (int i = 0; i < RTB; ++i) acc[i] = 0.f;
  for (int d = sl * 512; d < sl * 512 + 512; ++d) {
    float w = Wr[(size_t)d * NEXP + e];
#pragma unroll
    for (int i = 0; i < RTB; ++i) acc[i] += xp[(size_t)i * DM + d] * w;
  }
#pragma unroll
  for (int i = 0; i < RTB; ++i) part[sl][i][e] = acc[i];
  __syncthreads();
  for (int i = sl; i < RTB; i += 4)
    logits[i][e] = part[0][i][e] + part[1][i][e] + part[2][i][e] + part[3][i][e] + bias[e];
  __syncthreads();
  int lane = t & 63, wv = t >> 6;
  for (int i = wv * 2; i < wv * 2 + 2; ++i) {
    float lg = logits[i][lane];
    float m = lg;
#pragma unroll
    for (int o = 32; o; o >>= 1) m = fmaxf(m, __shfl_xor(m, o));
    float p = expf(lg - m);
    float sm = p;
#pragma unroll
    for (int o = 32; o; o >>= 1) sm += __shfl_xor(sm, o);
    float v = p / sm;
    float s0, s1, s2, s3; int i0, i1, i2, i3;
    ARGMAX_ROUND(s0, i0)
    ARGMAX_ROUND(s1, i1)
    ARGMAX_ROUND(s2, i2)
    ARGMAX_ROUND(s3, i3)
    float tot = s0 + s1 + s2 + s3;
    if (lane < TOPK) {
      float myw = (lane == 0 ? s0 : lane == 1 ? s1 : lane == 2 ? s2 : s3) / tot;
      int   mye = (lane == 0 ? i0 : lane == 1 ? i1 : lane == 2 ? i2 : i3);
      int pos = atomicAdd(&cnt[mye], 1);
      if (pos < CAPC) {
        lists[mye * CAPC + pos] = tok0 + i;
        wlist[mye * CAPC + pos] = myw;
      }
    }
  }
}

// ---------------------------------------------------------------- offsets
__global__ void k_offs(const int* __restrict__ cnt, int* __restrict__ offs) {
  int l = threadIdx.x;            // 64 threads
  int c = min(cnt[l], CAPC);
  int sum = c;
#pragma unroll
  for (int o = 1; o < 64; o <<= 1) {
    int ov = __shfl_up(sum, o);
    if (l >= o) sum += ov;
  }
  offs[l + 1] = sum;
  if (l == 0) offs[0] = 0;
}

// ---------------------------------------------------------------- GEMM pieces
// M-tile 256 (4 waves stacked in M), BN=32, BK=32.
// A LDS: [256 r][32 k] bf16 (64B rows), DMA-linear; source 16B chunk
//   pre-permuted c^=((row>>1)&3); read XOR byte^=((row>>1)&3)<<4.
// B LDS: [32 k][32 n] fp32 (128B rows), DMA-linear; source 4-float chunk
//   pre-permuted c^=((k>>3)&1)<<2; read col n^=((k>>3)&1)<<4  -> 2-way (free).

static __device__ __forceinline__ short8 frag_ldA(const unsigned short* lds, int row, int kElem) {
  int byte = row * 64 + kElem * 2;
  byte ^= ((row >> 1) & 3) << 4;
  return *(const short8*)((const char*)lds + byte);
}

static __device__ __forceinline__ short8 bfragB(const float* lB, int nl, int kb) {
  const float* p = lB + kb * 32 + (nl ^ (((kb >> 3) & 1) << 4));
  float f0 = p[0],   f1 = p[32],  f2 = p[64],  f3 = p[96];
  float f4_ = p[128], f5 = p[160], f6 = p[192], f7 = p[224];
  unsigned u0, u1, u2, u3;
  asm("v_cvt_pk_bf16_f32 %0, %1, %2" : "=v"(u0) : "v"(f0),  "v"(f1));
  asm("v_cvt_pk_bf16_f32 %0, %1, %2" : "=v"(u1) : "v"(f2),  "v"(f3));
  asm("v_cvt_pk_bf16_f32 %0, %1, %2" : "=v"(u2) : "v"(f4_), "v"(f5));
  asm("v_cvt_pk_bf16_f32 %0, %1, %2" : "=v"(u3) : "v"(f6),  "v"(f7));
  uint4v uv = {u0, u1, u2, u3};
  return __builtin_bit_cast(short8, uv);
}

static __device__ __forceinline__ void mma1f(const unsigned short* lA, const float* lB,
    f32x4 (&acc)[4][2], int wm, int lane) {
  int r16 = lane & 15;
  int kb  = (lane >> 4) * 8;
  short8 a[4], b[2];
#pragma unroll
  for (int mf = 0; mf < 4; ++mf) a[mf] = frag_ldA(lA, wm + mf * 16 + r16, kb);
#pragma unroll
  for (int nf = 0; nf < 2; ++nf) b[nf] = bfragB(lB, nf * 16 + r16, kb);
#pragma unroll
  for (int mf = 0; mf < 4; ++mf)
#pragma unroll
    for (int nf = 0; nf < 2; ++nf)
      acc[mf][nf] = __builtin_amdgcn_mfma_f32_16x16x32_bf16(a[mf], b[nf], acc[mf][nf], 0, 0, 0);
}

static __device__ __forceinline__ void mma2f(const unsigned short* lA,
    const float* lBg, const float* lBu,
    f32x4 (&accg)[4][2], f32x4 (&accu)[4][2], int wm, int lane) {
  int r16 = lane & 15;
  int kb  = (lane >> 4) * 8;
  short8 a[4], bg[2], bu[2];
#pragma unroll
  for (int mf = 0; mf < 4; ++mf) a[mf] = frag_ldA(lA, wm + mf * 16 + r16, kb);
#pragma unroll
  for (int nf = 0; nf < 2; ++nf) {
    bg[nf] = bfragB(lBg, nf * 16 + r16, kb);
    bu[nf] = bfragB(lBu, nf * 16 + r16, kb);
  }
#pragma unroll
  for (int mf = 0; mf < 4; ++mf)
#pragma unroll
    for (int nf = 0; nf < 2; ++nf) {
      accg[mf][nf] = __builtin_amdgcn_mfma_f32_16x16x32_bf16(a[mf], bg[nf], accg[mf][nf], 0, 0, 0);
      accu[mf][nf] = __builtin_amdgcn_mfma_f32_16x16x32_bf16(a[mf], bu[nf], accu[mf][nf], 0, 0, 0);
    }
}

static __device__ __forceinline__ float silu_mul(float g, float u) {
  return g / (1.f + expf(-g)) * u;
}

// A: 4 DMA rounds/wave/tile. Round p: row = wv*64 + p*16 + (lane>>2), chunk lane&3.
#define A_SETUP(asrc, SROW_EXPR)                                            \
  const unsigned short* asrc[4];                                            \
  { _Pragma("unroll")                                                       \
    for (int p = 0; p < 4; ++p) {                                           \
      int row = wv * 64 + p * 16 + (lane >> 2);                             \
      int srow = (SROW_EXPR);                                               \
      asrc[p] = Abase + (size_t)srow * lda                                  \
              + (((lane & 3) ^ ((row >> 1) & 3)) << 3);                     \
    } }
#define A_STAGE(asrc, lAbuf, k0)                                            \
  { _Pragma("unroll")                                                       \
    for (int p = 0; p < 4; ++p)                                             \
      GLDS16(asrc[p] + (k0), (lAbuf) + wv * 2048 + p * 512); }

// B: 1 DMA round/wave/tile. k = wv*8 + (lane>>3), 4-float chunk lane&7.
#define B_SETUP(bsrc, Bbase, ldb)                                           \
  const float* bsrc;                                                        \
  { int k = wv * 8 + (lane >> 3);                                           \
    int c = (lane & 7) ^ (((k >> 3) & 1) << 2);                             \
    bsrc = (Bbase) + (size_t)k * (ldb) + n0 + c * 4; }
#define B_STAGE(bsrc, lBbuf, k0, ldb)                                       \
  GLDS16((bsrc) + (size_t)(k0) * (ldb), (lBbuf) + wv * 256)

// ---------------------------------------------------------------- expert gate+up
// grid: 1024 blocks = 64 e x 16 nb (BN=32). M=256 covers any realistic ne.
__global__ __launch_bounds__(256, 3) void k_expert_gateup(const unsigned short* __restrict__ xbf,
    const float* __restrict__ Wg, const float* __restrict__ Wu,
    const int* __restrict__ cnt, const int* __restrict__ offs,
    const int* __restrict__ lists, unsigned short* __restrict__ hws) {
  int bid = swz_xcd(blockIdx.x, NEXP * (HEXP / 32));
  int e  = bid >> 4;
  int n0 = (bid & 15) * 32;
  int ne = min(cnt[e], CAPC);
  if (ne == 0) return;
  const float* Bg = Wg + (size_t)e * DM * HEXP;
  const float* Bu = Wu + (size_t)e * DM * HEXP;
  const int* lst = lists + e * CAPC;
  int base = offs[e];
  __shared__ unsigned short lA[2][256 * 32];
  __shared__ float lBg[2][32 * 32];
  __shared__ float lBu[2][32 * 32];
  int tid = threadIdx.x;
  int lane = tid & 63, wv = tid >> 6;
  int wm = wv * 64;
  const unsigned short* Abase = xbf; const int lda = DM;
  B_SETUP(bgsrc, Bg, HEXP)
  B_SETUP(busrc, Bu, HEXP)
  const int NT = DM / 32;           // 64
  for (int m0 = 0; m0 < ne; m0 += 256) {
    A_SETUP(asrc, lst[min(m0 + row, ne - 1)])
    f32x4 accg[4][2] = {};
    f32x4 accu[4][2] = {};
    A_STAGE(asrc, lA[0], 0)  B_STAGE(bgsrc, lBg[0], 0, HEXP);  B_STAGE(busrc, lBu[0], 0, HEXP);
    A_STAGE(asrc, lA[1], 32) B_STAGE(bgsrc, lBg[1], 32, HEXP); B_STAGE(busrc, lBu[1], 32, HEXP);
    VMWAIT(6); BARX();
#pragma unroll 1
    for (int t = 0; t < NT; t += 2) {
      mma2f(lA[0], lBg[0], lBu[0], accg, accu, wm, lane);
      BARX();
      if (t + 2 < NT) {
        int k2 = (t + 2) * 32;
        A_STAGE(asrc, lA[0], k2) B_STAGE(bgsrc, lBg[0], k2, HEXP); B_STAGE(busrc, lBu[0], k2, HEXP);
        VMWAIT(6);
      } else { VMWAIT(0); }
      BARX();
      mma2f(lA[1], lBg[1], lBu[1], accg, accu, wm, lane);
      if (t + 2 < NT) {
        BARX();
        if (t + 3 < NT) {
          int k3 = (t + 3) * 32;
          A_STAGE(asrc, lA[1], k3) B_STAGE(bgsrc, lBg[1], k3, HEXP); B_STAGE(busrc, lBu[1], k3, HEXP);
          VMWAIT(6);
        } else { VMWAIT(0); }
        BARX();
      }
    }
    BARX();   // protect LDS reuse across m0 iterations
#pragma unroll
    for (int mf = 0; mf < 4; ++mf)
#pragma unroll
      for (int r = 0; r < 4; ++r) {
        int rl = m0 + wm + mf * 16 + (lane >> 4) * 4 + r;
        if (rl < ne) {
#pragma unroll
          for (int nf = 0; nf < 2; ++nf) {
            int col = n0 + nf * 16 + (lane & 15);
            float h = silu_mul(accg[mf][nf][r], accu[mf][nf][r]);
            hws[(size_t)(base + rl) * HEXP + col] = f2bf(h);
          }
        }
      }
  }
}

// ---------------------------------------------------------------- shared gate+up
// grid: 1024 = 2 s x 8 mb x 64 nb
__global__ __launch_bounds__(256, 3) void k_shared_gateup(const unsigned short* __restrict__ xbf,
    const float* __restrict__ Sg, const float* __restrict__ Su,
    unsigned short* __restrict__ hs) {
  int bid = swz_xcd(blockIdx.x, NSH * (N_TOK / 256) * (HSH / 32));
  int nb = bid & 63, mb = (bid >> 6) & 7, s = bid >> 9;
  int n0 = nb * 32, m0 = mb * 256;
  const float* Bg = Sg + (size_t)s * DM * HSH;
  const float* Bu = Su + (size_t)s * DM * HSH;
  __shared__ unsigned short lA[2][256 * 32];
  __shared__ float lBg[2][32 * 32];
  __shared__ float lBu[2][32 * 32];
  int tid = threadIdx.x;
  int lane = tid & 63, wv = tid >> 6;
  int wm = wv * 64;
  const unsigned short* Abase = xbf; const int lda = DM;
  B_SETUP(bgsrc, Bg, HSH)
  B_SETUP(busrc, Bu, HSH)
  A_SETUP(asrc, m0 + row)
  f32x4 accg[4][2] = {};
  f32x4 accu[4][2] = {};
  const int NT = DM / 32;           // 64
  A_STAGE(asrc, lA[0], 0)  B_STAGE(bgsrc, lBg[0], 0, HSH);  B_STAGE(busrc, lBu[0], 0, HSH);
  A_STAGE(asrc, lA[1], 32) B_STAGE(bgsrc, lBg[1], 32, HSH); B_STAGE(busrc, lBu[1], 32, HSH);
  VMWAIT(6); BARX();
#pragma unroll 1
  for (int t = 0; t < NT; t += 2) {
    mma2f(lA[0], lBg[0], lBu[0], accg, accu, wm, lane);
    BARX();
    if (t + 2 < NT) {
      int k2 = (t + 2) * 32;
      A_STAGE(asrc, lA[0], k2) B_STAGE(bgsrc, lBg[0], k2, HSH); B_STAGE(busrc, lBu[0], k2, HSH);
      VMWAIT(6);
    } else { VMWAIT(0); }
    BARX();
    mma2f(lA[1], lBg[1], lBu[1], accg, accu, wm, lane);
    if (t + 2 < NT) {
      BARX();
      if (t + 3 < NT) {
        int k3 = (t + 3) * 32;
        A_STAGE(asrc, lA[1], k3) B_STAGE(bgsrc, lBg[1], k3, HSH); B_STAGE(busrc, lBu[1], k3, HSH);
        VMWAIT(6);
      } else { VMWAIT(0); }
      BARX();
    }
  }
#pragma unroll
  for (int mf = 0; mf < 4; ++mf)
#pragma unroll
    for (int nf = 0; nf < 2; ++nf)
#pragma unroll
      for (int r = 0; r < 4; ++r) {
        int row = m0 + wm + mf * 16 + (lane >> 4) * 4 + r;
        int col = n0 + nf * 16 + (lane & 15);
        float h = silu_mul(accg[mf][nf][r], accu[mf][nf][r]);
        hs[(size_t)row * (NSH * HSH) + s * HSH + col] = f2bf(h);
      }
}

// ---------------------------------------------------------------- shared down (writes out)
// grid: 512 = 8 mb x 64 nb
__global__ __launch_bounds__(256, 4) void k_shared_down(const unsigned short* __restrict__ hs,
    const float* __restrict__ Sd, float* __restrict__ out) {
  int bid = swz_xcd(blockIdx.x, (N_TOK / 256) * (DM / 32));
  int nb = bid & 63, mb = bid >> 6;
  int n0 = nb * 32, m0 = mb * 256;
  __shared__ unsigned short lA[2][256 * 32];
  __shared__ float lB[2][32 * 32];
  int tid = threadIdx.x;
  int lane = tid & 63, wv = tid >> 6;
  int wm = wv * 64;
  const unsigned short* Abase = hs; const int lda = NSH * HSH;
  B_SETUP(bsrc, Sd, DM)
  A_SETUP(asrc, m0 + row)
  f32x4 acc[4][2] = {};
  const int NT = (NSH * HSH) / 32;  // 128
  A_STAGE(asrc, lA[0], 0)  B_STAGE(bsrc, lB[0], 0, DM);
  A_STAGE(asrc, lA[1], 32) B_STAGE(bsrc, lB[1], 32, DM);
  VMWAIT(5); BARX();
#pragma unroll 1
  for (int t = 0; t < NT; t += 2) {
    mma1f(lA[0], lB[0], acc, wm, lane);
    BARX();
    if (t + 2 < NT) {
      int k2 = (t + 2) * 32;
      A_STAGE(asrc, lA[0], k2) B_STAGE(bsrc, lB[0], k2, DM);
      VMWAIT(5);
    } else { VMWAIT(0); }
    BARX();
    mma1f(lA[1], lB[1], acc, wm, lane);
    if (t + 2 < NT) {
      BARX();
      if (t + 3 < NT) {
        int k3 = (t + 3) * 32;
        A_STAGE(asrc, lA[1], k3) B_STAGE(bsrc, lB[1], k3, DM);
        VMWAIT(5);
      } else { VMWAIT(0); }
      BARX();
    }
  }
#pragma unroll
  for (int mf = 0; mf < 4; ++mf)
#pragma unroll
    for (int nf = 0; nf < 2; ++nf)
#pragma unroll
      for (int r = 0; r < 4; ++r) {
        int row = m0 + wm + mf * 16 + (lane >> 4) * 4 + r;
        int col = n0 + nf * 16 + (lane & 15);
        out[(size_t)row * DM + col] = acc[mf][nf][r];
      }
}

// ---------------------------------------------------------------- expert down (atomic add)
// grid: 4096 = 64 e x 64 nb (BN=32)
__global__ __launch_bounds__(256, 4) void k_expert_down(const unsigned short* __restrict__ hws,
    const float* __restrict__ Wd, const int* __restrict__ cnt, const int* __restrict__ offs,
    const int* __restrict__ lists, const float* __restrict__ wlist,
    float* __restrict__ out) {
  int bid = swz_xcd(blockIdx.x, NEXP * (DM / 32));
  int e  = bid >> 6;
  int n0 = (bid & 63) * 32;
  int ne = min(cnt[e], CAPC);
  if (ne == 0) return;
  const float* B = Wd + (size_t)e * HEXP * DM;
  __shared__ unsigned short lA[2][256 * 32];
  __shared__ float lB[2][32 * 32];
  int tid = threadIdx.x;
  int lane = tid & 63, wv = tid >> 6;
  int wm = wv * 64;
  const unsigned short* Abase = hws + (size_t)offs[e] * HEXP; const int lda = HEXP;
  B_SETUP(bsrc, B, DM)
  const int NT = HEXP / 32;         // 16
  for (int m0 = 0; m0 < ne; m0 += 256) {
    A_SETUP(asrc, min(m0 + row, ne - 1))
    f32x4 acc[4][2] = {};
    A_STAGE(asrc, lA[0], 0)  B_STAGE(bsrc, lB[0], 0, DM);
    A_STAGE(asrc, lA[1], 32) B_STAGE(bsrc, lB[1], 32, DM);
    VMWAIT(5); BARX();
#pragma unroll 1
    for (int t = 0; t < NT; t += 2) {
      mma1f(lA[0], lB[0], acc, wm, lane);
      BARX();
      if (t + 2 < NT) {
        int k2 = (t + 2) * 32;
        A_STAGE(asrc, lA[0], k2) B_STAGE(bsrc, lB[0], k2, DM);
        VMWAIT(5);
      } else { VMWAIT(0); }
      BARX();
      mma1f(lA[1], lB[1], acc, wm, lane);
      if (t + 2 < NT) {
        BARX();
        if (t + 3 < NT) {
          int k3 = (t + 3) * 32;
          A_STAGE(asrc, lA[1], k3) B_STAGE(bsrc, lB[1], k3, DM);
          VMWAIT(5);
        } else { VMWAIT(0); }
        BARX();
      }
    }
    BARX();   // protect LDS reuse across m0 iterations
#pragma unroll
    for (int mf = 0; mf < 4; ++mf)
#pragma unroll
      for (int r = 0; r < 4; ++r) {
        int rl = m0 + wm + mf * 16 + (lane >> 4) * 4 + r;
        if (rl < ne) {
          int tok  = lists[e * CAPC + rl];
          float w  = wlist[e * CAPC + rl];
#pragma unroll
          for (int nf = 0; nf < 2; ++nf) {
            int col = n0 + nf * 16 + (lane & 15);
            atomicAdd(out + (size_t)tok * DM + col, acc[mf][nf][r] * w);
          }
        }
      }
  }
}

// ---------------------------------------------------------------- launch
extern "C" void kernel_launch(void* const* d_in, const int* in_sizes, int n_in,
                              void* d_out, int out_size, void* d_ws, size_t ws_size,
                              hipStream_t stream) {
  const float* x    = (const float*)d_in[0];
  const float* Wr   = (const float*)d_in[1];
  const float* bias = (const float*)d_in[2];
  const float* Wg   = (const float*)d_in[3];
  const float* Wu   = (const float*)d_in[4];
  const float* Wd   = (const float*)d_in[5];
  const float* Sg   = (const float*)d_in[6];
  const float* Su   = (const float*)d_in[7];
  const float* Sd   = (const float*)d_in[8];
  float* out = (float*)d_out;
  char* ws = (char*)d_ws;

  const size_t off_cnt   = 0;
  const size_t off_offs  = 256;
  const size_t off_lists = 1024;
  const size_t off_wlist = off_lists + (size_t)NEXP * CAPC * 4;
  const size_t off_xbf   = off_wlist + (size_t)NEXP * CAPC * 4;
  const size_t off_hs    = off_xbf + (size_t)N_TOK * DM * 2;
  const size_t off_h     = off_hs + (size_t)N_TOK * NSH * HSH * 2;
  const size_t req       = off_h + (size_t)N_TOK * TOPK * HEXP * 2;
  if (ws_size < req) return;   // loud failure, no corruption

  int* cnt            = (int*)(ws + off_cnt);
  int* offs           = (int*)(ws + off_offs);
  int* lists          = (int*)(ws + off_lists);
  float* wlist        = (float*)(ws + off_wlist);
  unsigned short* xbf = (unsigned short*)(ws + off_xbf);
  unsigned short* hs  = (unsigned short*)(ws + off_hs);
  unsigned short* hws = (unsigned short*)(ws + off_h);

  hipMemsetAsync(cnt, 0, NEXP * sizeof(int), stream);
  k_convert<<<(N_TOK * DM) / (256 * 8), 256, 0, stream>>>(x, xbf);
  k_router<<<N_TOK / RTB, 256, 0, stream>>>(x, Wr, bias, cnt, lists, wlist);
  k_offs<<<1, 64, 0, stream>>>(cnt, offs);
  k_expert_gateup<<<NEXP * (HEXP / 32), 256, 0, stream>>>(xbf, Wg, Wu, cnt, offs, lists, hws);
  k_shared_gateup<<<NSH * (N_TOK / 256) * (HSH / 32), 256, 0, stream>>>(xbf, Sg, Su, hs);
  k_shared_down<<<(N_TOK / 256) * (DM / 32), 256, 0, stream>>>(hs, Sd, out);
  k_expert_down<<<NEXP * (DM / 32), 256, 0, stream>>>(hws, Wd, cnt, offs, lists, wlist, out);
}